// Round 6
// baseline (301.585 us; speedup 1.0000x reference)
//
#include <hip/hip_runtime.h>
#include <math.h>

// Problem constants
#define B_   64
#define N_   197
#define C_   768
#define H_   12
#define HD_  64
#define BH_  (B_ * H_)          // 768
#define M_   (B_ * N_)          // 12608

typedef _Float16 half8 __attribute__((ext_vector_type(8)));
typedef float    f32x4 __attribute__((ext_vector_type(4)));

// MFMA NT-GEMM tile: 128x128 block, BK=32 halves, 4 waves (2x2 of 64x64),
// double-buffered LDS (one barrier per K-iter)
#define MLDS 40   // LDS row stride (halves): 80 B, 16B-aligned
#define LBUF (128 * MLDS)

// Workspace byte offsets (16B aligned); XH/WQH/WPH contiguous for merged cvt
#define XH_OFF   0u           // 12608*768 fp16        = 19,365,888
#define WQH_OFF  19365888u    // 2304*768 fp16         =  3,538,944
#define WPH_OFF  22904832u    // 768*768 fp16          =  1,179,648
#define QH_OFF   24084480u    // [bh][197][64] fp16
#define KH_OFF   43450368u    // [bh][197][64] fp16
#define VT_OFF   62816256u    // [bh][64][224] fp16 (V transposed, key-padded)
#define OH_OFF   84836352u    // [B][N][C] fp16
#define P0_OFF   104202240u   // [bh][196] fp32
#define WS_BYTES 104804352u

// merged-cvt source spans (in units of 8 floats)
#define X_N8   1210368
#define WQ_N8  221184
#define TOT_N8 1505280        // + 73728 for w_proj

__device__ __forceinline__ half8 h8zero() {
    half8 z;
    #pragma unroll
    for (int i = 0; i < 8; ++i) z[i] = (_Float16)0;
    return z;
}

// ---------------------------------------------------------------------------
__global__ void k_ws_too_small(float* out, float ws_bytes) { out[0] = -ws_bytes; }

// ---------------------------------------------------------------------------
// fp32 -> fp16 bulk convert of x, w_qkv, w_proj into the contiguous
// XH|WQH|WPH region in one launch.
__global__ __launch_bounds__(256) void k_cvt_all(const float* __restrict__ x,
                                                 const float* __restrict__ wq,
                                                 const float* __restrict__ wp,
                                                 _Float16* __restrict__ dst) {
    const int i = blockIdx.x * 256 + threadIdx.x;
    if (i >= TOT_N8) return;
    const float* src;
    size_t off;
    if (i < X_N8)               { src = x;  off = (size_t)i * 8; }
    else if (i < X_N8 + WQ_N8)  { src = wq; off = (size_t)(i - X_N8) * 8; }
    else                        { src = wp; off = (size_t)(i - X_N8 - WQ_N8) * 8; }
    float4 f0 = *(const float4*)(src + off);
    float4 f1 = *(const float4*)(src + off + 4);
    half8 h;
    h[0]=(_Float16)f0.x; h[1]=(_Float16)f0.y; h[2]=(_Float16)f0.z; h[3]=(_Float16)f0.w;
    h[4]=(_Float16)f1.x; h[5]=(_Float16)f1.y; h[6]=(_Float16)f1.z; h[7]=(_Float16)f1.w;
    *(half8*)(dst + (size_t)i * 8) = h;
}

// zero Vt key-halves [192,224) per [bh][d] row; runs BEFORE k_qkv (which
// rewrites valid keys 192..196), leaving 197..223 zero.
__global__ __launch_bounds__(256) void k_vpad(_Float16* __restrict__ Vt) {
    const int i = blockIdx.x * 256 + threadIdx.x;   // 768*64*4 = 196608 exact
    const int row = i >> 2, c = i & 3;
    *(half8*)&Vt[(size_t)row * 224 + 192 + c * 8] = h8zero();
}

// ---------------------------------------------------------------------------
// NT-GEMM core (r4-proven structure + LDS double-buffer): fp16 inputs,
// register prefetch of next chunk, ONE barrier per K-iter.
// A-frag: lane holds A[m=lane&15][k=(lane>>4)*8+j]; C/D: col=lane&15, row=quad*4+reg
__device__ __forceinline__ void mfma_nt_core_h(const _Float16* __restrict__ A,
                                               const _Float16* __restrict__ B,
                                               int M, int K, int m0, int n0,
                                               _Float16* As, _Float16* Bs,
                                               f32x4 (&acc)[4][4]) {
    const int tid  = threadIdx.x;
    const int r    = tid >> 1;             // 0..127 staging row
    const int c0   = (tid & 1) << 4;       // 0 or 16 halves
    const int wave = tid >> 6, lane = tid & 63;
    const int wr   = (wave >> 1) << 6;
    const int wc   = (wave & 1) << 6;
    const int ln   = lane & 15, kq = lane >> 4;

    const int  ag   = m0 + r;
    const bool aval = ag < M;
    const _Float16* Ap = A + (size_t)(aval ? ag : 0) * K + c0;
    const _Float16* Bp = B + (size_t)(n0 + r) * K + c0;

    half8 a0 = *(const half8*)(Ap),     a1 = *(const half8*)(Ap + 8);
    half8 b0 = *(const half8*)(Bp),     b1 = *(const half8*)(Bp + 8);
    if (!aval) { a0 = h8zero(); a1 = h8zero(); }

    int buf = 0;
    for (int k0 = 0; k0 < K; k0 += 32, buf ^= 1) {
        _Float16* Aw = As + buf * LBUF;
        _Float16* Bw = Bs + buf * LBUF;
        // writes go to the buffer nobody is reading this iteration
        *(half8*)&Aw[r * MLDS + c0]     = a0;
        *(half8*)&Aw[r * MLDS + c0 + 8] = a1;
        *(half8*)&Bw[r * MLDS + c0]     = b0;
        *(half8*)&Bw[r * MLDS + c0 + 8] = b1;
        __syncthreads();                     // single barrier: writes visible
        if (k0 + 32 < K) {                   // prefetch next chunk (overlaps MFMA)
            a0 = *(const half8*)(Ap + k0 + 32); a1 = *(const half8*)(Ap + k0 + 40);
            b0 = *(const half8*)(Bp + k0 + 32); b1 = *(const half8*)(Bp + k0 + 40);
            if (!aval) { a0 = h8zero(); a1 = h8zero(); }
        }
        half8 af[4], bf[4];
        #pragma unroll
        for (int t = 0; t < 4; ++t) {
            af[t] = *(const half8*)&Aw[(wr + t * 16 + ln) * MLDS + kq * 8];
            bf[t] = *(const half8*)&Bw[(wc + t * 16 + ln) * MLDS + kq * 8];
        }
        #pragma unroll
        for (int i = 0; i < 4; ++i)
            #pragma unroll
            for (int j = 0; j < 4; ++j)
                acc[i][j] = __builtin_amdgcn_mfma_f32_16x16x32_f16(af[i], bf[j], acc[i][j], 0, 0, 0);
    }
}

// ---------------------------------------------------------------------------
// qkv = x @ w_qkv^T; epilogue scatters Q(x0.125)/K -> [bh][n][64], V -> Vt[bh][d][224]
__global__ __launch_bounds__(256) void k_qkv_mfma(const _Float16* __restrict__ Xh,
                                                  const _Float16* __restrict__ Wq,
                                                  _Float16* __restrict__ Qh,
                                                  _Float16* __restrict__ Kh,
                                                  _Float16* __restrict__ Vt) {
    __shared__ _Float16 As[2 * LBUF];
    __shared__ _Float16 Bs[2 * LBUF];
    const int m0 = blockIdx.y << 7;
    const int n0 = blockIdx.x << 7;
    f32x4 acc[4][4] = {};
    mfma_nt_core_h(Xh, Wq, M_, C_, m0, n0, As, Bs, acc);

    const int lane = threadIdx.x & 63;
    const int wave = threadIdx.x >> 6;
    const int wr = (wave >> 1) << 6, wc = (wave & 1) << 6;
    const int ln = lane & 15, kq = lane >> 4;
    #pragma unroll
    for (int mt = 0; mt < 4; ++mt) {
        #pragma unroll
        for (int i = 0; i < 4; ++i) {
            const int m = m0 + wr + mt * 16 + kq * 4 + i;
            if (m >= M_) continue;
            const int b = m / N_;
            const int n = m - b * N_;
            #pragma unroll
            for (int nt = 0; nt < 4; ++nt) {
                const int d  = n0 + wc + nt * 16 + ln;
                const int t3 = d / C_;
                const int rr = d - t3 * C_;
                const int h  = rr >> 6;
                const int e  = rr & 63;
                const int bh = b * H_ + h;
                const float v = acc[mt][nt][i];
                if      (t3 == 0) Qh[((size_t)bh * N_ + n) * HD_ + e] = (_Float16)(v * 0.125f);
                else if (t3 == 1) Kh[((size_t)bh * N_ + n) * HD_ + e] = (_Float16)v;
                else              Vt[((size_t)bh * HD_ + e) * 224 + n] = (_Float16)v;
            }
        }
    }
}

// ---------------------------------------------------------------------------
// out = O @ w_proj^T + b_proj
__global__ __launch_bounds__(256) void k_proj_mfma(const _Float16* __restrict__ Oh,
                                                   const _Float16* __restrict__ Wp,
                                                   const float* __restrict__ bias,
                                                   float* __restrict__ out) {
    __shared__ _Float16 As[2 * LBUF];
    __shared__ _Float16 Bs[2 * LBUF];
    const int m0 = blockIdx.y << 7;
    const int n0 = blockIdx.x << 7;
    f32x4 acc[4][4] = {};
    mfma_nt_core_h(Oh, Wp, M_, C_, m0, n0, As, Bs, acc);

    const int lane = threadIdx.x & 63;
    const int wave = threadIdx.x >> 6;
    const int wr = (wave >> 1) << 6, wc = (wave & 1) << 6;
    const int ln = lane & 15, kq = lane >> 4;
    float bv[4];
    #pragma unroll
    for (int nt = 0; nt < 4; ++nt) bv[nt] = bias[n0 + wc + nt * 16 + ln];
    #pragma unroll
    for (int mt = 0; mt < 4; ++mt) {
        #pragma unroll
        for (int i = 0; i < 4; ++i) {
            const int m = m0 + wr + mt * 16 + kq * 4 + i;
            if (m >= M_) continue;
            #pragma unroll
            for (int nt = 0; nt < 4; ++nt)
                out[(size_t)m * C_ + n0 + wc + nt * 16 + ln] = acc[mt][nt][i] + bv[nt];
        }
    }
}

// ---------------------------------------------------------------------------
// Fused attention, per (64-row tile rt, bh). K and V fragments direct from
// global (L2/L3-resident; V pre-transposed as Vt with zero pads). Only P does
// the LDS round-trip (C-layout -> A-layout). One barrier total.
__global__ __launch_bounds__(256) void k_attn(const _Float16* __restrict__ Qh,
                                              const _Float16* __restrict__ Kh,
                                              const _Float16* __restrict__ Vt,
                                              _Float16* __restrict__ Oh,
                                              float* __restrict__ P0) {
    __shared__ _Float16 Pl[4 * 16 * 232];    // per-wave 16x232 strip
    const int bh = blockIdx.y, rt = blockIdx.x;
    const int b = bh / H_, h = bh - b * H_;
    const int tid = threadIdx.x, wave = tid >> 6, lane = tid & 63;
    const int ln = lane & 15, kq = lane >> 4;
    const size_t kvb = (size_t)bh * N_ * HD_;
    const size_t vtb = (size_t)bh * HD_ * 224;

    // Q A-fragments direct from global
    const int qrow = rt * 64 + wave * 16 + ln;
    const _Float16* Qp = Qh + kvb + (size_t)((qrow < N_) ? qrow : 0) * HD_ + kq * 8;
    const half8 qf0 = *(const half8*)Qp;
    const half8 qf1 = *(const half8*)(Qp + 32);

    // S = Q K^T over 13 key tiles; K B-frags direct from global.
    // Keys 197..207 read neighboring data (finite) and are masked below.
    f32x4 acc[13] = {};
    #pragma unroll
    for (int c = 0; c < 13; ++c) {
        const _Float16* kp = Kh + kvb + (size_t)(c * 16 + ln) * HD_ + kq * 8;
        const half8 kf0 = *(const half8*)kp;
        const half8 kf1 = *(const half8*)(kp + 32);
        acc[c] = __builtin_amdgcn_mfma_f32_16x16x32_f16(qf0, kf0, acc[c], 0, 0, 0);
        acc[c] = __builtin_amdgcn_mfma_f32_16x16x32_f16(qf1, kf1, acc[c], 0, 0, 0);
    }
    // softmax per row (lane holds rows kq*4+r, cols c*16+ln); mask cols>=197
    float inv4[4];
    #pragma unroll
    for (int r = 0; r < 4; ++r) {
        float m = -1e30f;
        #pragma unroll
        for (int c = 0; c < 13; ++c) {
            float x = ((c * 16 + ln) < N_) ? acc[c][r] : -1e30f;
            acc[c][r] = x;
            m = fmaxf(m, x);
        }
        m = fmaxf(m, __shfl_xor(m, 1)); m = fmaxf(m, __shfl_xor(m, 2));
        m = fmaxf(m, __shfl_xor(m, 4)); m = fmaxf(m, __shfl_xor(m, 8));
        float s = 0.f;
        #pragma unroll
        for (int c = 0; c < 13; ++c) { float e = __expf(acc[c][r] - m); acc[c][r] = e; s += e; }
        s += __shfl_xor(s, 1); s += __shfl_xor(s, 2);
        s += __shfl_xor(s, 4); s += __shfl_xor(s, 8);
        inv4[r] = 1.f / s;
    }

    // P (fp16) -> own LDS strip; cols 197..207 are exp(-1e30)=0, 208..223 zeroed
    _Float16* Pw = Pl + wave * 16 * 232;
    #pragma unroll
    for (int c = 0; c < 13; ++c) {
        const int col = c * 16 + ln;
        #pragma unroll
        for (int r = 0; r < 4; ++r)
            Pw[(kq * 4 + r) * 232 + col] = (_Float16)(acc[c][r] * inv4[r]);
    }
    #pragma unroll
    for (int r = 0; r < 4; ++r) Pw[(kq * 4 + r) * 232 + 208 + ln] = (_Float16)0;

    // CLS-row probs for global_attn (row 0 = rt0/wave0/quad0/reg0)
    if (rt == 0 && wave == 0 && kq == 0) {
        #pragma unroll
        for (int c = 0; c < 13; ++c) {
            const int col = c * 16 + ln;
            if (col >= 1 && col < N_) P0[(size_t)bh * 196 + col - 1] = acc[c][0] * inv4[0];
        }
    }
    __syncthreads();   // P strip visible before A-frag reads

    // O = P V: A-frags from LDS strip, B-frags direct from global Vt (pads zero)
    f32x4 o4[4] = {};
    #pragma unroll
    for (int t = 0; t < 7; ++t) {
        const half8 pf = *(const half8*)&Pw[ln * 232 + kq * 8 + 32 * t];
        #pragma unroll
        for (int n = 0; n < 4; ++n) {
            const half8 vf = *(const half8*)(Vt + vtb + (size_t)(n * 16 + ln) * 224 + kq * 8 + 32 * t);
            o4[n] = __builtin_amdgcn_mfma_f32_16x16x32_f16(pf, vf, o4[n], 0, 0, 0);
        }
    }
    // store O fp16 [B][N][C]
    const int g0 = rt * 64 + wave * 16 + kq * 4;
    #pragma unroll
    for (int r = 0; r < 4; ++r) {
        const int g = g0 + r;
        if (g >= N_) continue;
        _Float16* op = Oh + ((size_t)b * N_ + g) * C_ + h * HD_;
        #pragma unroll
        for (int n = 0; n < 4; ++n) op[n * 16 + ln] = (_Float16)o4[n][r];
    }
}

// ---------------------------------------------------------------------------
// global_attn[b][m] = mean_h P0[b*12+h][m]
__global__ void k_gattn(const float* __restrict__ P0, float* __restrict__ out2) {
    const int idx = blockIdx.x * blockDim.x + threadIdx.x;   // 12544 exact
    const int b = idx / (N_ - 1), m = idx - b * (N_ - 1);
    float s = 0.f;
    #pragma unroll
    for (int h = 0; h < H_; ++h) s += P0[((size_t)(b * H_ + h)) * 196 + m];
    out2[idx] = s * (1.f / H_);
}

// ---------------------------------------------------------------------------
extern "C" void kernel_launch(void* const* d_in, const int* in_sizes, int n_in,
                              void* d_out, int out_size, void* d_ws, size_t ws_size,
                              hipStream_t stream) {
    const float* x      = (const float*)d_in[0];
    const float* w_qkv  = (const float*)d_in[1];
    const float* w_proj = (const float*)d_in[2];
    const float* b_proj = (const float*)d_in[3];
    float* out = (float*)d_out;
    char* ws   = (char*)d_ws;

    if (ws_size < (size_t)WS_BYTES) {
        k_ws_too_small<<<1, 1, 0, stream>>>(out, (float)ws_size);
        return;
    }

    _Float16* Xh  = (_Float16*)(ws + XH_OFF);
    _Float16* Wqh = (_Float16*)(ws + WQH_OFF);
    _Float16* Wph = (_Float16*)(ws + WPH_OFF);
    _Float16* Qh  = (_Float16*)(ws + QH_OFF);
    _Float16* Kh  = (_Float16*)(ws + KH_OFF);
    _Float16* Vt  = (_Float16*)(ws + VT_OFF);
    _Float16* Oh  = (_Float16*)(ws + OH_OFF);
    float*    P0  = (float*)   (ws + P0_OFF);

    k_cvt_all<<<5880, 256, 0, stream>>>(x, w_qkv, w_proj, Xh);  // XH|WQH|WPH contiguous
    k_vpad   <<<768,  256, 0, stream>>>(Vt);

    k_qkv_mfma <<<dim3(18, 99), 256, 0, stream>>>(Xh, Wqh, Qh, Kh, Vt);
    k_attn     <<<dim3(4, BH_), 256, 0, stream>>>(Qh, Kh, Vt, Oh, P0);
    k_gattn    <<<dim3(49),     256, 0, stream>>>(P0, out + (size_t)M_ * C_);
    k_proj_mfma<<<dim3(6, 99),  256, 0, stream>>>(Oh, Wph, b_proj, out);
}

// Round 7
// 294.517 us; speedup vs baseline: 1.0240x; 1.0240x over previous
//
#include <hip/hip_runtime.h>
#include <math.h>

// Problem constants
#define B_   64
#define N_   197
#define C_   768
#define H_   12
#define HD_  64
#define BH_  (B_ * H_)          // 768
#define M_   (B_ * N_)          // 12608

typedef _Float16 half8 __attribute__((ext_vector_type(8)));
typedef float    f32x4 __attribute__((ext_vector_type(4)));

// MFMA NT-GEMM tile (r4-proven): 128x128 block, BK=32 halves, single LDS buffer,
// register prefetch. Do NOT re-add double-buffering / global_load_lds here:
// both measured slower at K=768 (r5: 101us, r6: 117us vs r4: 86us).
#define MLDS 40   // LDS row stride (halves): 80 B, 16B-aligned

// Workspace byte offsets (16B aligned); XH/WQH/WPH contiguous for merged cvt
#define XH_OFF   0u           // 12608*768 fp16        = 19,365,888
#define WQH_OFF  19365888u    // 2304*768 fp16         =  3,538,944
#define WPH_OFF  22904832u    // 768*768 fp16          =  1,179,648
#define QH_OFF   24084480u    // [bh][197][64] fp16
#define KH_OFF   43450368u    // [bh][197][64] fp16
#define VT_OFF   62816256u    // [bh][64][224] fp16 (V transposed, key-padded)
#define OH_OFF   84836352u    // [B][N][C] fp16
#define WS_BYTES 104804352u

// merged-prep spans (units of 8 floats / half8)
#define X_N8     1210368
#define WQ_N8    221184
#define TOT_N8   1505280      // + 73728 for w_proj
#define CVT_BLK  5880         // TOT_N8 / 256
#define VPAD_BLK 768          // 768*64*4 / 256

__device__ __forceinline__ half8 h8zero() {
    half8 z;
    #pragma unroll
    for (int i = 0; i < 8; ++i) z[i] = (_Float16)0;
    return z;
}

// ---------------------------------------------------------------------------
__global__ void k_ws_too_small(float* out, float ws_bytes) { out[0] = -ws_bytes; }

// ---------------------------------------------------------------------------
// Merged prep: blocks [0, CVT_BLK) convert x|w_qkv|w_proj fp32->fp16 into the
// contiguous XH|WQH|WPH region; blocks [CVT_BLK, CVT_BLK+VPAD_BLK) zero the
// Vt key-pad halves [192,224) (k_qkv later rewrites valid keys 192..196).
__global__ __launch_bounds__(256) void k_prep(const float* __restrict__ x,
                                              const float* __restrict__ wq,
                                              const float* __restrict__ wp,
                                              _Float16* __restrict__ dst,
                                              _Float16* __restrict__ Vt) {
    const int gb = blockIdx.x;
    if (gb < CVT_BLK) {
        const int i = gb * 256 + threadIdx.x;
        if (i >= TOT_N8) return;
        const float* src;
        size_t off;
        if (i < X_N8)              { src = x;  off = (size_t)i * 8; }
        else if (i < X_N8 + WQ_N8) { src = wq; off = (size_t)(i - X_N8) * 8; }
        else                       { src = wp; off = (size_t)(i - X_N8 - WQ_N8) * 8; }
        float4 f0 = *(const float4*)(src + off);
        float4 f1 = *(const float4*)(src + off + 4);
        half8 h;
        h[0]=(_Float16)f0.x; h[1]=(_Float16)f0.y; h[2]=(_Float16)f0.z; h[3]=(_Float16)f0.w;
        h[4]=(_Float16)f1.x; h[5]=(_Float16)f1.y; h[6]=(_Float16)f1.z; h[7]=(_Float16)f1.w;
        *(half8*)(dst + (size_t)i * 8) = h;
    } else {
        const int i = (gb - CVT_BLK) * 256 + threadIdx.x;   // 196608 exact
        const int row = i >> 2, c = i & 3;
        *(half8*)&Vt[(size_t)row * 224 + 192 + c * 8] = h8zero();
    }
}

// ---------------------------------------------------------------------------
// NT-GEMM core (r4-proven): fp16 inputs, register prefetch of next chunk,
// single LDS buffer, two barriers per K-iter.
// A-frag: lane holds A[m=lane&15][k=(lane>>4)*8+j]; C/D: col=lane&15, row=quad*4+reg
__device__ __forceinline__ void mfma_nt_core_h(const _Float16* __restrict__ A,
                                               const _Float16* __restrict__ B,
                                               int M, int K, int m0, int n0,
                                               _Float16* As, _Float16* Bs,
                                               f32x4 (&acc)[4][4]) {
    const int tid  = threadIdx.x;
    const int r    = tid >> 1;             // 0..127 staging row
    const int c0   = (tid & 1) << 4;       // 0 or 16 halves
    const int wave = tid >> 6, lane = tid & 63;
    const int wr   = (wave >> 1) << 6;
    const int wc   = (wave & 1) << 6;
    const int ln   = lane & 15, kq = lane >> 4;

    const int  ag   = m0 + r;
    const bool aval = ag < M;
    const _Float16* Ap = A + (size_t)(aval ? ag : 0) * K + c0;
    const _Float16* Bp = B + (size_t)(n0 + r) * K + c0;

    half8 a0 = *(const half8*)(Ap),     a1 = *(const half8*)(Ap + 8);
    half8 b0 = *(const half8*)(Bp),     b1 = *(const half8*)(Bp + 8);
    if (!aval) { a0 = h8zero(); a1 = h8zero(); }

    for (int k0 = 0; k0 < K; k0 += 32) {
        __syncthreads();                     // prior iter's frag reads done
        *(half8*)&As[r * MLDS + c0]     = a0;
        *(half8*)&As[r * MLDS + c0 + 8] = a1;
        *(half8*)&Bs[r * MLDS + c0]     = b0;
        *(half8*)&Bs[r * MLDS + c0 + 8] = b1;
        __syncthreads();
        if (k0 + 32 < K) {                   // prefetch next chunk (overlaps MFMA)
            a0 = *(const half8*)(Ap + k0 + 32); a1 = *(const half8*)(Ap + k0 + 40);
            b0 = *(const half8*)(Bp + k0 + 32); b1 = *(const half8*)(Bp + k0 + 40);
            if (!aval) { a0 = h8zero(); a1 = h8zero(); }
        }
        half8 af[4], bf[4];
        #pragma unroll
        for (int t = 0; t < 4; ++t) {
            af[t] = *(const half8*)&As[(wr + t * 16 + ln) * MLDS + kq * 8];
            bf[t] = *(const half8*)&Bs[(wc + t * 16 + ln) * MLDS + kq * 8];
        }
        #pragma unroll
        for (int i = 0; i < 4; ++i)
            #pragma unroll
            for (int j = 0; j < 4; ++j)
                acc[i][j] = __builtin_amdgcn_mfma_f32_16x16x32_f16(af[i], bf[j], acc[i][j], 0, 0, 0);
    }
}

// ---------------------------------------------------------------------------
// qkv = x @ w_qkv^T; epilogue scatters Q(x0.125)/K -> [bh][n][64], V -> Vt[bh][d][224]
__global__ __launch_bounds__(256) void k_qkv_mfma(const _Float16* __restrict__ Xh,
                                                  const _Float16* __restrict__ Wq,
                                                  _Float16* __restrict__ Qh,
                                                  _Float16* __restrict__ Kh,
                                                  _Float16* __restrict__ Vt) {
    __shared__ _Float16 As[128 * MLDS];
    __shared__ _Float16 Bs[128 * MLDS];
    const int m0 = blockIdx.y << 7;
    const int n0 = blockIdx.x << 7;
    f32x4 acc[4][4] = {};
    mfma_nt_core_h(Xh, Wq, M_, C_, m0, n0, As, Bs, acc);

    const int lane = threadIdx.x & 63;
    const int wave = threadIdx.x >> 6;
    const int wr = (wave >> 1) << 6, wc = (wave & 1) << 6;
    const int ln = lane & 15, kq = lane >> 4;
    #pragma unroll
    for (int mt = 0; mt < 4; ++mt) {
        #pragma unroll
        for (int i = 0; i < 4; ++i) {
            const int m = m0 + wr + mt * 16 + kq * 4 + i;
            if (m >= M_) continue;
            const int b = m / N_;
            const int n = m - b * N_;
            #pragma unroll
            for (int nt = 0; nt < 4; ++nt) {
                const int d  = n0 + wc + nt * 16 + ln;
                const int t3 = d / C_;
                const int rr = d - t3 * C_;
                const int h  = rr >> 6;
                const int e  = rr & 63;
                const int bh = b * H_ + h;
                const float v = acc[mt][nt][i];
                if      (t3 == 0) Qh[((size_t)bh * N_ + n) * HD_ + e] = (_Float16)(v * 0.125f);
                else if (t3 == 1) Kh[((size_t)bh * N_ + n) * HD_ + e] = (_Float16)v;
                else              Vt[((size_t)bh * HD_ + e) * 224 + n] = (_Float16)v;
            }
        }
    }
}

// ---------------------------------------------------------------------------
// out = O @ w_proj^T + b_proj
__global__ __launch_bounds__(256) void k_proj_mfma(const _Float16* __restrict__ Oh,
                                                   const _Float16* __restrict__ Wp,
                                                   const float* __restrict__ bias,
                                                   float* __restrict__ out) {
    __shared__ _Float16 As[128 * MLDS];
    __shared__ _Float16 Bs[128 * MLDS];
    const int m0 = blockIdx.y << 7;
    const int n0 = blockIdx.x << 7;
    f32x4 acc[4][4] = {};
    mfma_nt_core_h(Oh, Wp, M_, C_, m0, n0, As, Bs, acc);

    const int lane = threadIdx.x & 63;
    const int wave = threadIdx.x >> 6;
    const int wr = (wave >> 1) << 6, wc = (wave & 1) << 6;
    const int ln = lane & 15, kq = lane >> 4;
    float bv[4];
    #pragma unroll
    for (int nt = 0; nt < 4; ++nt) bv[nt] = bias[n0 + wc + nt * 16 + ln];
    #pragma unroll
    for (int mt = 0; mt < 4; ++mt) {
        #pragma unroll
        for (int i = 0; i < 4; ++i) {
            const int m = m0 + wr + mt * 16 + kq * 4 + i;
            if (m >= M_) continue;
            #pragma unroll
            for (int nt = 0; nt < 4; ++nt)
                out[(size_t)m * C_ + n0 + wc + nt * 16 + ln] = acc[mt][nt][i] + bv[nt];
        }
    }
}

// ---------------------------------------------------------------------------
// Fused attention, per (64-row tile rt, bh). K/V fragments direct from global
// (L2-resident; Vt pre-transposed, zero-padded). P's C->A layout transform
// round-trips through a WAVE-PRIVATE LDS strip — no block barrier anywhere.
// CLS-row (rt0) probs accumulate the head-mean directly into out2 (atomics;
// out2 zeroed by hipMemsetAsync before launch).
__global__ __launch_bounds__(256) void k_attn(const _Float16* __restrict__ Qh,
                                              const _Float16* __restrict__ Kh,
                                              const _Float16* __restrict__ Vt,
                                              _Float16* __restrict__ Oh,
                                              float* __restrict__ out2) {
    __shared__ _Float16 Pl[4 * 16 * 232];    // per-wave 16x232 strip
    const int bh = blockIdx.y, rt = blockIdx.x;
    const int b = bh / H_, h = bh - b * H_;
    const int tid = threadIdx.x, wave = tid >> 6, lane = tid & 63;
    const int ln = lane & 15, kq = lane >> 4;
    const size_t kvb = (size_t)bh * N_ * HD_;
    const size_t vtb = (size_t)bh * HD_ * 224;

    // Q A-fragments direct from global
    const int qrow = rt * 64 + wave * 16 + ln;
    const _Float16* Qp = Qh + kvb + (size_t)((qrow < N_) ? qrow : 0) * HD_ + kq * 8;
    const half8 qf0 = *(const half8*)Qp;
    const half8 qf1 = *(const half8*)(Qp + 32);

    // S = Q K^T over 13 key tiles; K B-frags direct from global.
    // Keys 197..207 read adjacent workspace (finite) and are masked below.
    f32x4 acc[13] = {};
    #pragma unroll
    for (int c = 0; c < 13; ++c) {
        const _Float16* kp = Kh + kvb + (size_t)(c * 16 + ln) * HD_ + kq * 8;
        const half8 kf0 = *(const half8*)kp;
        const half8 kf1 = *(const half8*)(kp + 32);
        acc[c] = __builtin_amdgcn_mfma_f32_16x16x32_f16(qf0, kf0, acc[c], 0, 0, 0);
        acc[c] = __builtin_amdgcn_mfma_f32_16x16x32_f16(qf1, kf1, acc[c], 0, 0, 0);
    }
    // softmax per row (lane holds rows kq*4+r, cols c*16+ln); mask cols>=197
    float inv4[4];
    #pragma unroll
    for (int r = 0; r < 4; ++r) {
        float m = -1e30f;
        #pragma unroll
        for (int c = 0; c < 13; ++c) {
            float x = ((c * 16 + ln) < N_) ? acc[c][r] : -1e30f;
            acc[c][r] = x;
            m = fmaxf(m, x);
        }
        m = fmaxf(m, __shfl_xor(m, 1)); m = fmaxf(m, __shfl_xor(m, 2));
        m = fmaxf(m, __shfl_xor(m, 4)); m = fmaxf(m, __shfl_xor(m, 8));
        float s = 0.f;
        #pragma unroll
        for (int c = 0; c < 13; ++c) { float e = __expf(acc[c][r] - m); acc[c][r] = e; s += e; }
        s += __shfl_xor(s, 1); s += __shfl_xor(s, 2);
        s += __shfl_xor(s, 4); s += __shfl_xor(s, 8);
        inv4[r] = 1.f / s;
    }

    // P (fp16) -> own wave-private LDS strip; cols 197..207 = exp(masked) = 0,
    // 208..223 zeroed. Intra-wave RAW ordered via lgkmcnt — no barrier needed.
    _Float16* Pw = Pl + wave * 16 * 232;
    #pragma unroll
    for (int c = 0; c < 13; ++c) {
        const int col = c * 16 + ln;
        #pragma unroll
        for (int r = 0; r < 4; ++r)
            Pw[(kq * 4 + r) * 232 + col] = (_Float16)(acc[c][r] * inv4[r]);
    }
    #pragma unroll
    for (int r = 0; r < 4; ++r) Pw[(kq * 4 + r) * 232 + 208 + ln] = (_Float16)0;

    // CLS-row head-mean directly into out2 (row 0 = rt0/wave0/quad0/reg0)
    if (rt == 0 && wave == 0 && kq == 0) {
        const float w = inv4[0] * (1.f / (float)H_);
        #pragma unroll
        for (int c = 0; c < 13; ++c) {
            const int col = c * 16 + ln;
            if (col >= 1 && col < N_)
                atomicAdd(out2 + (size_t)b * (N_ - 1) + col - 1, acc[c][0] * w);
        }
    }

    // O = P V: A-frags from wave-private LDS strip, B-frags direct from Vt
    f32x4 o4[4] = {};
    #pragma unroll
    for (int t = 0; t < 7; ++t) {
        const half8 pf = *(const half8*)&Pw[ln * 232 + kq * 8 + 32 * t];
        #pragma unroll
        for (int n = 0; n < 4; ++n) {
            const half8 vf = *(const half8*)(Vt + vtb + (size_t)(n * 16 + ln) * 224 + kq * 8 + 32 * t);
            o4[n] = __builtin_amdgcn_mfma_f32_16x16x32_f16(pf, vf, o4[n], 0, 0, 0);
        }
    }
    // store O fp16 [B][N][C]
    const int g0 = rt * 64 + wave * 16 + kq * 4;
    #pragma unroll
    for (int r = 0; r < 4; ++r) {
        const int g = g0 + r;
        if (g >= N_) continue;
        _Float16* op = Oh + ((size_t)b * N_ + g) * C_ + h * HD_;
        #pragma unroll
        for (int n = 0; n < 4; ++n) op[n * 16 + ln] = (_Float16)o4[n][r];
    }
}

// ---------------------------------------------------------------------------
extern "C" void kernel_launch(void* const* d_in, const int* in_sizes, int n_in,
                              void* d_out, int out_size, void* d_ws, size_t ws_size,
                              hipStream_t stream) {
    const float* x      = (const float*)d_in[0];
    const float* w_qkv  = (const float*)d_in[1];
    const float* w_proj = (const float*)d_in[2];
    const float* b_proj = (const float*)d_in[3];
    float* out = (float*)d_out;
    char* ws   = (char*)d_ws;

    if (ws_size < (size_t)WS_BYTES) {
        k_ws_too_small<<<1, 1, 0, stream>>>(out, (float)ws_size);
        return;
    }

    _Float16* Xh  = (_Float16*)(ws + XH_OFF);
    _Float16* Wqh = (_Float16*)(ws + WQH_OFF);
    _Float16* Wph = (_Float16*)(ws + WPH_OFF);
    _Float16* Qh  = (_Float16*)(ws + QH_OFF);
    _Float16* Kh  = (_Float16*)(ws + KH_OFF);
    _Float16* Vt  = (_Float16*)(ws + VT_OFF);
    _Float16* Oh  = (_Float16*)(ws + OH_OFF);
    float*    out2 = out + (size_t)M_ * C_;

    hipMemsetAsync(out2, 0, (size_t)B_ * (N_ - 1) * sizeof(float), stream);

    k_prep     <<<CVT_BLK + VPAD_BLK, 256, 0, stream>>>(x, w_qkv, w_proj, Xh, Vt);
    k_qkv_mfma <<<dim3(18, 99), 256, 0, stream>>>(Xh, Wqh, Qh, Kh, Vt);
    k_attn     <<<dim3(4, BH_), 256, 0, stream>>>(Qh, Kh, Vt, Oh, out2);
    k_proj_mfma<<<dim3(6, 99),  256, 0, stream>>>(Oh, Wph, b_proj, out);
}

// Round 8
// 281.934 us; speedup vs baseline: 1.0697x; 1.0446x over previous
//
#include <hip/hip_runtime.h>
#include <math.h>

// Problem constants
#define B_   64
#define N_   197
#define C_   768
#define H_   12
#define HD_  64
#define BH_  (B_ * H_)          // 768
#define M_   (B_ * N_)          // 12608

typedef _Float16 half8 __attribute__((ext_vector_type(8)));
typedef float    f32x4 __attribute__((ext_vector_type(4)));

// MFMA NT-GEMM tile (r4-proven): 128x128 block, BK=32 halves, single LDS buffer,
// register prefetch. Measured dead ends — do NOT reintroduce:
//  * global_load_lds m97 core (r5: 101us) — too few K-iters at K=768
//  * LDS double-buffer (r6: 117us)
//  * V-transposed scatter in the GEMM epilogue (r7: 111us, +24MB write amp)
#define MLDS 40   // LDS row stride (halves): 80 B, 16B-aligned

// Workspace byte offsets (16B aligned); XH/WQH/WPH contiguous for merged cvt
#define XH_OFF   0u           // 12608*768 fp16        = 19,365,888
#define WQH_OFF  19365888u    // 2304*768 fp16         =  3,538,944
#define WPH_OFF  22904832u    // 768*768 fp16          =  1,179,648
#define QH_OFF   24084480u    // [bh][197][64] fp16
#define KH_OFF   43450368u    // [bh][197][64] fp16
#define VT_OFF   62816256u    // [bh][64][224] fp16 (V transposed, key-padded)
#define OH_OFF   84836352u    // [B][N][C] fp16; ALSO aliases Vh[bh][197][64]
                              // (Vh dead after k_vt, Oh written by k_attn after)
#define WS_BYTES 104804352u

// merged-cvt spans (units of 8 floats / half8)
#define X_N8     1210368
#define WQ_N8    221184
#define TOT_N8   1505280      // + 73728 for w_proj
#define CVT_BLK  5880         // TOT_N8 / 256

__device__ __forceinline__ half8 h8zero() {
    half8 z;
    #pragma unroll
    for (int i = 0; i < 8; ++i) z[i] = (_Float16)0;
    return z;
}

// ---------------------------------------------------------------------------
__global__ void k_ws_too_small(float* out, float ws_bytes) { out[0] = -ws_bytes; }

// ---------------------------------------------------------------------------
// fp32 -> fp16 bulk convert of x|w_qkv|w_proj into contiguous XH|WQH|WPH
__global__ __launch_bounds__(256) void k_cvt(const float* __restrict__ x,
                                             const float* __restrict__ wq,
                                             const float* __restrict__ wp,
                                             _Float16* __restrict__ dst) {
    const int i = blockIdx.x * 256 + threadIdx.x;
    if (i >= TOT_N8) return;
    const float* src;
    size_t off;
    if (i < X_N8)              { src = x;  off = (size_t)i * 8; }
    else if (i < X_N8 + WQ_N8) { src = wq; off = (size_t)(i - X_N8) * 8; }
    else                       { src = wp; off = (size_t)(i - X_N8 - WQ_N8) * 8; }
    float4 f0 = *(const float4*)(src + off);
    float4 f1 = *(const float4*)(src + off + 4);
    half8 h;
    h[0]=(_Float16)f0.x; h[1]=(_Float16)f0.y; h[2]=(_Float16)f0.z; h[3]=(_Float16)f0.w;
    h[4]=(_Float16)f1.x; h[5]=(_Float16)f1.y; h[6]=(_Float16)f1.z; h[7]=(_Float16)f1.w;
    *(half8*)(dst + (size_t)i * 8) = h;
}

// ---------------------------------------------------------------------------
// V transpose: Vh[bh][key][64] -> Vt[bh][d][224] (keys 197..223 zero).
// Coalesced global read -> LDS transpose -> coalesced global write.
__global__ __launch_bounds__(256) void k_vt(const _Float16* __restrict__ Vh,
                                            _Float16* __restrict__ Vt) {
    __shared__ _Float16 Vl[64 * 232];   // [d][key], stride 232 (rows 16B-aligned)
    const int bh = blockIdx.x;
    const int tid = threadIdx.x;
    const size_t vb = (size_t)bh * N_ * HD_;

    // zero keys 192..223 (staging below rewrites valid 192..196)
    for (int i = tid; i < 64 * 32; i += 256) {
        const int d = i >> 5, k = 192 + (i & 31);
        Vl[d * 232 + k] = (_Float16)0;
    }
    __syncthreads();
    // stage: read Vh rows coalesced, scatter into Vl[d][key]
    for (int i = tid; i < 197 * 8; i += 256) {
        const int key = i >> 3, c = (i & 7) << 3;
        half8 v = *(const half8*)(Vh + vb + (size_t)key * HD_ + c);
        #pragma unroll
        for (int j = 0; j < 8; ++j) Vl[(c + j) * 232 + key] = v[j];
    }
    __syncthreads();
    // write out coalesced: 64 d-rows x 28 half8
    const size_t tb = (size_t)bh * HD_ * 224;
    for (int i = tid; i < 64 * 28; i += 256) {
        const int d = i / 28, k8 = (i - d * 28) << 3;
        *(half8*)(Vt + tb + (size_t)d * 224 + k8) = *(const half8*)&Vl[d * 232 + k8];
    }
}

// ---------------------------------------------------------------------------
// NT-GEMM core (r4-proven): fp16 inputs, register prefetch of next chunk,
// single LDS buffer, two barriers per K-iter.
// A-frag: lane holds A[m=lane&15][k=(lane>>4)*8+j]; C/D: col=lane&15, row=quad*4+reg
__device__ __forceinline__ void mfma_nt_core_h(const _Float16* __restrict__ A,
                                               const _Float16* __restrict__ B,
                                               int M, int K, int m0, int n0,
                                               _Float16* As, _Float16* Bs,
                                               f32x4 (&acc)[4][4]) {
    const int tid  = threadIdx.x;
    const int r    = tid >> 1;             // 0..127 staging row
    const int c0   = (tid & 1) << 4;       // 0 or 16 halves
    const int wave = tid >> 6, lane = tid & 63;
    const int wr   = (wave >> 1) << 6;
    const int wc   = (wave & 1) << 6;
    const int ln   = lane & 15, kq = lane >> 4;

    const int  ag   = m0 + r;
    const bool aval = ag < M;
    const _Float16* Ap = A + (size_t)(aval ? ag : 0) * K + c0;
    const _Float16* Bp = B + (size_t)(n0 + r) * K + c0;

    half8 a0 = *(const half8*)(Ap),     a1 = *(const half8*)(Ap + 8);
    half8 b0 = *(const half8*)(Bp),     b1 = *(const half8*)(Bp + 8);
    if (!aval) { a0 = h8zero(); a1 = h8zero(); }

    for (int k0 = 0; k0 < K; k0 += 32) {
        __syncthreads();                     // prior iter's frag reads done
        *(half8*)&As[r * MLDS + c0]     = a0;
        *(half8*)&As[r * MLDS + c0 + 8] = a1;
        *(half8*)&Bs[r * MLDS + c0]     = b0;
        *(half8*)&Bs[r * MLDS + c0 + 8] = b1;
        __syncthreads();
        if (k0 + 32 < K) {                   // prefetch next chunk (overlaps MFMA)
            a0 = *(const half8*)(Ap + k0 + 32); a1 = *(const half8*)(Ap + k0 + 40);
            b0 = *(const half8*)(Bp + k0 + 32); b1 = *(const half8*)(Bp + k0 + 40);
            if (!aval) { a0 = h8zero(); a1 = h8zero(); }
        }
        half8 af[4], bf[4];
        #pragma unroll
        for (int t = 0; t < 4; ++t) {
            af[t] = *(const half8*)&As[(wr + t * 16 + ln) * MLDS + kq * 8];
            bf[t] = *(const half8*)&Bs[(wc + t * 16 + ln) * MLDS + kq * 8];
        }
        #pragma unroll
        for (int i = 0; i < 4; ++i)
            #pragma unroll
            for (int j = 0; j < 4; ++j)
                acc[i][j] = __builtin_amdgcn_mfma_f32_16x16x32_f16(af[i], bf[j], acc[i][j], 0, 0, 0);
    }
}

// ---------------------------------------------------------------------------
// qkv = x @ w_qkv^T; r4-proven epilogue: Q(x0.125)/K/V all row-coalesced
// into [bh][n][64] (V transposed later by k_vt).
__global__ __launch_bounds__(256) void k_qkv_mfma(const _Float16* __restrict__ Xh,
                                                  const _Float16* __restrict__ Wq,
                                                  _Float16* __restrict__ Qh,
                                                  _Float16* __restrict__ Kh,
                                                  _Float16* __restrict__ Vh) {
    __shared__ _Float16 As[128 * MLDS];
    __shared__ _Float16 Bs[128 * MLDS];
    const int m0 = blockIdx.y << 7;
    const int n0 = blockIdx.x << 7;
    f32x4 acc[4][4] = {};
    mfma_nt_core_h(Xh, Wq, M_, C_, m0, n0, As, Bs, acc);

    const int lane = threadIdx.x & 63;
    const int wave = threadIdx.x >> 6;
    const int wr = (wave >> 1) << 6, wc = (wave & 1) << 6;
    const int ln = lane & 15, kq = lane >> 4;
    #pragma unroll
    for (int mt = 0; mt < 4; ++mt) {
        #pragma unroll
        for (int i = 0; i < 4; ++i) {
            const int m = m0 + wr + mt * 16 + kq * 4 + i;
            if (m >= M_) continue;
            const int b = m / N_;
            const int n = m - b * N_;
            #pragma unroll
            for (int nt = 0; nt < 4; ++nt) {
                const int d  = n0 + wc + nt * 16 + ln;
                const int t3 = d / C_;            // 0=q 1=k 2=v (n-tiles are pure)
                const int rr = d - t3 * C_;
                const int h  = rr >> 6;
                const int e  = rr & 63;
                const size_t off = ((size_t)((b * H_ + h) * N_ + n)) * HD_ + e;
                const float v = acc[mt][nt][i];
                if      (t3 == 0) Qh[off] = (_Float16)(v * 0.125f);
                else if (t3 == 1) Kh[off] = (_Float16)v;
                else              Vh[off] = (_Float16)v;
            }
        }
    }
}

// ---------------------------------------------------------------------------
// out = O @ w_proj^T + b_proj
__global__ __launch_bounds__(256) void k_proj_mfma(const _Float16* __restrict__ Oh,
                                                   const _Float16* __restrict__ Wp,
                                                   const float* __restrict__ bias,
                                                   float* __restrict__ out) {
    __shared__ _Float16 As[128 * MLDS];
    __shared__ _Float16 Bs[128 * MLDS];
    const int m0 = blockIdx.y << 7;
    const int n0 = blockIdx.x << 7;
    f32x4 acc[4][4] = {};
    mfma_nt_core_h(Oh, Wp, M_, C_, m0, n0, As, Bs, acc);

    const int lane = threadIdx.x & 63;
    const int wave = threadIdx.x >> 6;
    const int wr = (wave >> 1) << 6, wc = (wave & 1) << 6;
    const int ln = lane & 15, kq = lane >> 4;
    float bv[4];
    #pragma unroll
    for (int nt = 0; nt < 4; ++nt) bv[nt] = bias[n0 + wc + nt * 16 + ln];
    #pragma unroll
    for (int mt = 0; mt < 4; ++mt) {
        #pragma unroll
        for (int i = 0; i < 4; ++i) {
            const int m = m0 + wr + mt * 16 + kq * 4 + i;
            if (m >= M_) continue;
            #pragma unroll
            for (int nt = 0; nt < 4; ++nt)
                out[(size_t)m * C_ + n0 + wc + nt * 16 + ln] = acc[mt][nt][i] + bv[nt];
        }
    }
}

// ---------------------------------------------------------------------------
// Fused attention, per (64-row tile rt, bh). K/V fragments direct from global
// (L2-resident; Vt pre-transposed, zero-padded). P's C->A layout transform
// round-trips through a WAVE-PRIVATE LDS strip — no block barrier.
// CLS-row (rt0) probs accumulate the head-mean into out2 via atomics
// (out2 zeroed by hipMemsetAsync before launch).
__global__ __launch_bounds__(256) void k_attn(const _Float16* __restrict__ Qh,
                                              const _Float16* __restrict__ Kh,
                                              const _Float16* __restrict__ Vt,
                                              _Float16* __restrict__ Oh,
                                              float* __restrict__ out2) {
    __shared__ _Float16 Pl[4 * 16 * 232];    // per-wave 16x232 strip
    const int bh = blockIdx.y, rt = blockIdx.x;
    const int b = bh / H_, h = bh - b * H_;
    const int tid = threadIdx.x, wave = tid >> 6, lane = tid & 63;
    const int ln = lane & 15, kq = lane >> 4;
    const size_t kvb = (size_t)bh * N_ * HD_;
    const size_t vtb = (size_t)bh * HD_ * 224;

    // Q A-fragments direct from global
    const int qrow = rt * 64 + wave * 16 + ln;
    const _Float16* Qp = Qh + kvb + (size_t)((qrow < N_) ? qrow : 0) * HD_ + kq * 8;
    const half8 qf0 = *(const half8*)Qp;
    const half8 qf1 = *(const half8*)(Qp + 32);

    // S = Q K^T over 13 key tiles; K B-frags direct from global.
    // Keys 197..207 read adjacent workspace (finite) and are masked below.
    f32x4 acc[13] = {};
    #pragma unroll
    for (int c = 0; c < 13; ++c) {
        const _Float16* kp = Kh + kvb + (size_t)(c * 16 + ln) * HD_ + kq * 8;
        const half8 kf0 = *(const half8*)kp;
        const half8 kf1 = *(const half8*)(kp + 32);
        acc[c] = __builtin_amdgcn_mfma_f32_16x16x32_f16(qf0, kf0, acc[c], 0, 0, 0);
        acc[c] = __builtin_amdgcn_mfma_f32_16x16x32_f16(qf1, kf1, acc[c], 0, 0, 0);
    }
    // softmax per row (lane holds rows kq*4+r, cols c*16+ln); mask cols>=197
    float inv4[4];
    #pragma unroll
    for (int r = 0; r < 4; ++r) {
        float m = -1e30f;
        #pragma unroll
        for (int c = 0; c < 13; ++c) {
            float x = ((c * 16 + ln) < N_) ? acc[c][r] : -1e30f;
            acc[c][r] = x;
            m = fmaxf(m, x);
        }
        m = fmaxf(m, __shfl_xor(m, 1)); m = fmaxf(m, __shfl_xor(m, 2));
        m = fmaxf(m, __shfl_xor(m, 4)); m = fmaxf(m, __shfl_xor(m, 8));
        float s = 0.f;
        #pragma unroll
        for (int c = 0; c < 13; ++c) { float e = __expf(acc[c][r] - m); acc[c][r] = e; s += e; }
        s += __shfl_xor(s, 1); s += __shfl_xor(s, 2);
        s += __shfl_xor(s, 4); s += __shfl_xor(s, 8);
        inv4[r] = 1.f / s;
    }

    // P (fp16) -> own wave-private LDS strip; cols 197..207 = 0, 208..223 zeroed.
    _Float16* Pw = Pl + wave * 16 * 232;
    #pragma unroll
    for (int c = 0; c < 13; ++c) {
        const int col = c * 16 + ln;
        #pragma unroll
        for (int r = 0; r < 4; ++r)
            Pw[(kq * 4 + r) * 232 + col] = (_Float16)(acc[c][r] * inv4[r]);
    }
    #pragma unroll
    for (int r = 0; r < 4; ++r) Pw[(kq * 4 + r) * 232 + 208 + ln] = (_Float16)0;

    // CLS-row head-mean into out2 (row 0 = rt0/wave0/quad0/reg0)
    if (rt == 0 && wave == 0 && kq == 0) {
        const float w = inv4[0] * (1.f / (float)H_);
        #pragma unroll
        for (int c = 0; c < 13; ++c) {
            const int col = c * 16 + ln;
            if (col >= 1 && col < N_)
                atomicAdd(out2 + (size_t)b * (N_ - 1) + col - 1, acc[c][0] * w);
        }
    }

    // O = P V: A-frags from wave-private LDS strip, B-frags direct from Vt
    f32x4 o4[4] = {};
    #pragma unroll
    for (int t = 0; t < 7; ++t) {
        const half8 pf = *(const half8*)&Pw[ln * 232 + kq * 8 + 32 * t];
        #pragma unroll
        for (int n = 0; n < 4; ++n) {
            const half8 vf = *(const half8*)(Vt + vtb + (size_t)(n * 16 + ln) * 224 + kq * 8 + 32 * t);
            o4[n] = __builtin_amdgcn_mfma_f32_16x16x32_f16(pf, vf, o4[n], 0, 0, 0);
        }
    }
    // store O fp16 [B][N][C]
    const int g0 = rt * 64 + wave * 16 + kq * 4;
    #pragma unroll
    for (int r = 0; r < 4; ++r) {
        const int g = g0 + r;
        if (g >= N_) continue;
        _Float16* op = Oh + ((size_t)b * N_ + g) * C_ + h * HD_;
        #pragma unroll
        for (int n = 0; n < 4; ++n) op[n * 16 + ln] = (_Float16)o4[n][r];
    }
}

// ---------------------------------------------------------------------------
extern "C" void kernel_launch(void* const* d_in, const int* in_sizes, int n_in,
                              void* d_out, int out_size, void* d_ws, size_t ws_size,
                              hipStream_t stream) {
    const float* x      = (const float*)d_in[0];
    const float* w_qkv  = (const float*)d_in[1];
    const float* w_proj = (const float*)d_in[2];
    const float* b_proj = (const float*)d_in[3];
    float* out = (float*)d_out;
    char* ws   = (char*)d_ws;

    if (ws_size < (size_t)WS_BYTES) {
        k_ws_too_small<<<1, 1, 0, stream>>>(out, (float)ws_size);
        return;
    }

    _Float16* Xh  = (_Float16*)(ws + XH_OFF);
    _Float16* Wqh = (_Float16*)(ws + WQH_OFF);
    _Float16* Wph = (_Float16*)(ws + WPH_OFF);
    _Float16* Qh  = (_Float16*)(ws + QH_OFF);
    _Float16* Kh  = (_Float16*)(ws + KH_OFF);
    _Float16* Vt  = (_Float16*)(ws + VT_OFF);
    _Float16* Vh  = (_Float16*)(ws + OH_OFF);   // aliases Oh: Vh dead after k_vt
    _Float16* Oh  = (_Float16*)(ws + OH_OFF);
    float*    out2 = out + (size_t)M_ * C_;

    hipMemsetAsync(out2, 0, (size_t)B_ * (N_ - 1) * sizeof(float), stream);

    k_cvt      <<<CVT_BLK, 256, 0, stream>>>(x, w_qkv, w_proj, Xh);
    k_qkv_mfma <<<dim3(18, 99), 256, 0, stream>>>(Xh, Wqh, Qh, Kh, Vh);
    k_vt       <<<BH_, 256, 0, stream>>>(Vh, Vt);
    k_attn     <<<dim3(4, BH_), 256, 0, stream>>>(Qh, Kh, Vt, Oh, out2);
    k_proj_mfma<<<dim3(6, 99),  256, 0, stream>>>(Oh, Wph, b_proj, out);
}